// Round 7
// baseline (51.130 us; speedup 1.0000x reference)
//
#include <hip/hip_runtime.h>
#include <math.h>

#define MAXC 56      // member slots per bag (true max ~25); slot 63 = bag label
#define BLK  128     // 2 waves per block; 16 blocks/CU * 2 = 32 waves/CU at 8/SIMD
#define DD   690     // feature dim
#define NF2  345     // DD/2 float2 elements per row
#define NJ   6       // ceil(NF2/64)

__global__ void sa_scatter_kernel(const int* __restrict__ epid,
                                  const int* __restrict__ labels, int n_sent,
                                  int* __restrict__ counts, int* __restrict__ idxmat,
                                  float* __restrict__ out_lab, int P) {
    int i = blockIdx.x * blockDim.x + threadIdx.x;
    if (i >= n_sent) return;
    int q = epid[i];
    int r = atomicAdd(&counts[q], 1);
    if (r < MAXC) idxmat[(q << 6) + r] = i * DD;   // element offset, not index
    if (r == 0) {
        int lab = labels[i];                 // labels consistent within a bag
        idxmat[(q << 6) + 63] = lab;         // stash bag label next to the offsets
        out_lab[P - 1 - q] = (float)lab;     // second output written here
    }
}

// One wave per bag, single pass, no max-subtraction (scores ~N(0,0.5): exp is
// fp32-safe; epsilon differs ~1e-8 relative). Single-row A/B ping-pong keeps
// VGPR <= 64 so 8 waves/SIMD fit: all 8192 bags co-resident in one round.
__global__ __launch_bounds__(BLK, 8)
void sa_bag_wave_kernel(const float* __restrict__ inputs,
                        const float* __restrict__ emb,
                        const int* __restrict__ counts,
                        const int* __restrict__ idxmat,
                        float* __restrict__ out_att,
                        int P) {
    const int lane = threadIdx.x & 63;
    const int wid  = threadIdx.x >> 6;
    const int p = (blockIdx.x << 1) + wid;   // output bag index
    if (p >= P) return;
    const int q = P - 1 - p;                 // pair id (desc sort + reversed bincount)
    int cnt = counts[q];                     // L2-hot (scatter-dirty)
    if (cnt > MAXC) cnt = MAXC;
    const int* bag = idxmat + (q << 6);
    int myoff = (lane < cnt) ? bag[lane] : 0;   // element offset of this lane's row
    const int lab = bag[63];                 // stashed bag label

    // rel = emb[lab]: 146KB table -> L2/L3-resident
    const float2* rel2 = (const float2*)(emb + (size_t)lab * DD);
    float2 rel_r[NJ];
    #pragma unroll
    for (int j = 0; j < NJ; ++j) {
        int f = lane + 64 * j;
        rel_r[j] = (f < NF2) ? rel2[f] : make_float2(0.f, 0.f);
    }

    float2 acc[NJ];
    #pragma unroll
    for (int j = 0; j < NJ; ++j) acc[j] = make_float2(0.f, 0.f);
    float sw = 0.f;

    float2 A[NJ], B[NJ];

    auto load_row = [&](float2* r, int m) {
        int off = __shfl(myoff, m & 63);
        const float2* row = (const float2*)(inputs + off);
        #pragma unroll
        for (int j = 0; j < NJ; ++j) {
            int f = lane + 64 * j;
            r[j] = (f < NF2) ? row[f] : make_float2(0.f, 0.f);
        }
    };

    auto process = [&](const float2* r) {    // caller guarantees m < cnt
        float s = 0.f;
        #pragma unroll
        for (int j = 0; j < NJ; ++j) {
            s = fmaf(r[j].x, rel_r[j].x, s);
            s = fmaf(r[j].y, rel_r[j].y, s);
        }
        #pragma unroll
        for (int off = 32; off; off >>= 1) s += __shfl_xor(s, off);
        float w = __expf(s);
        sw += w;
        #pragma unroll
        for (int j = 0; j < NJ; ++j) {
            acc[j].x = fmaf(w, r[j].x, acc[j].x);
            acc[j].y = fmaf(w, r[j].y, acc[j].y);
        }
    };

    load_row(A, 0);
    int m = 0;
    for (;;) {
        if (m + 1 < cnt) load_row(B, m + 1);   // prefetch next row
        process(A);
        if (++m >= cnt) break;
        if (m + 1 < cnt) load_row(A, m + 1);
        process(B);
        if (++m >= cnt) break;
    }

    const float inv = 1.0f / (sw + 1e-8f);
    float2* out2 = (float2*)(out_att + (size_t)p * DD);
    #pragma unroll
    for (int j = 0; j < NJ; ++j) {
        int f = lane + 64 * j;
        if (f < NF2) out2[f] = make_float2(acc[j].x * inv, acc[j].y * inv);
    }
}

extern "C" void kernel_launch(void* const* d_in, const int* in_sizes, int n_in,
                              void* d_out, int out_size, void* d_ws, size_t ws_size,
                              hipStream_t stream) {
    const float* inputs = (const float*)d_in[0];
    const float* emb    = (const float*)d_in[1];
    const int*   labels = (const int*)d_in[2];
    const int*   epid   = (const int*)d_in[3];

    const int n_sent = in_sizes[2];
    const int P      = out_size / (DD + 1);      // 8192 (att P*D + labels P)

    int* counts = (int*)d_ws;                    // P ints
    int* idxmat = counts + P;                    // P*64 ints

    float* out_att = (float*)d_out;
    float* out_lab = out_att + (size_t)P * DD;

    hipMemsetAsync(counts, 0, (size_t)P * sizeof(int), stream);
    sa_scatter_kernel<<<(n_sent + 255) / 256, 256, 0, stream>>>(
        epid, labels, n_sent, counts, idxmat, out_lab, P);

    const int nblk = (P + 1) / 2;                // 2 bags (waves) per 128-thread block
    sa_bag_wave_kernel<<<nblk, BLK, 0, stream>>>(inputs, emb, counts, idxmat,
                                                 out_att, P);
}

// Round 8
// 48.825 us; speedup vs baseline: 1.0472x; 1.0472x over previous
//
#include <hip/hip_runtime.h>
#include <math.h>

#define MAXC 56      // member slots per bag (true max ~25); slot 63 = bag label
#define BLK  128     // 2 waves per block -> fine-grain block retirement
#define DD   690     // feature dim
#define NF2  345     // DD/2 float2 elements per row
#define NJ   6       // ceil(NF2/64)

__global__ void sa_scatter_kernel(const int* __restrict__ epid,
                                  const int* __restrict__ labels, int n_sent,
                                  int* __restrict__ counts, int* __restrict__ idxmat,
                                  float* __restrict__ out_lab, int P) {
    int i = blockIdx.x * blockDim.x + threadIdx.x;
    if (i >= n_sent) return;
    int q = epid[i];
    int r = atomicAdd(&counts[q], 1);
    if (r < MAXC) idxmat[(q << 6) + r] = i * DD;   // element offset, not index
    if (r == 0) {
        int lab = labels[i];                 // labels consistent within a bag
        idxmat[(q << 6) + 63] = lab;         // stash bag label next to the offsets
        out_lab[P - 1 - q] = (float)lab;     // second output written here
    }
}

// One wave per bag, single pass, no max-subtraction (scores ~N(0,0.5): exp is
// fp32-safe; epsilon differs ~1e-8 relative). 3-deep rotating row prefetch
// (A/B/C) at 4 waves/SIMD: ~48 rows in flight per CU. No LDS, no barriers.
__global__ __launch_bounds__(BLK, 4)
void sa_bag_wave_kernel(const float* __restrict__ inputs,
                        const float* __restrict__ emb,
                        const int* __restrict__ counts,
                        const int* __restrict__ idxmat,
                        float* __restrict__ out_att,
                        int P) {
    const int lane = threadIdx.x & 63;
    const int wid  = threadIdx.x >> 6;
    const int p = (blockIdx.x << 1) + wid;   // output bag index
    if (p >= P) return;
    const int q = P - 1 - p;                 // pair id (desc sort + reversed bincount)
    int cnt = counts[q];                     // L2-hot (scatter-dirty)
    if (cnt > MAXC) cnt = MAXC;
    const int* bag = idxmat + (q << 6);
    int myoff = (lane < cnt) ? bag[lane] : 0;   // element offset of this lane's row
    const int lab = bag[63];                 // stashed bag label (no labels[] hop)

    // rel = emb[lab]: 146KB table -> L2/L3-resident
    const float2* rel2 = (const float2*)(emb + (size_t)lab * DD);
    float2 rel_r[NJ];
    #pragma unroll
    for (int j = 0; j < NJ; ++j) {
        int f = lane + 64 * j;
        rel_r[j] = (f < NF2) ? rel2[f] : make_float2(0.f, 0.f);
    }

    float2 acc[NJ];
    #pragma unroll
    for (int j = 0; j < NJ; ++j) acc[j] = make_float2(0.f, 0.f);
    float sw = 0.f;

    float2 A[NJ], B[NJ], C[NJ];

    auto load_row = [&](float2* r, int m) {
        int off = __shfl(myoff, m & 63);     // m < 64 always (cnt <= 56, lookahead +2)
        const float2* row = (const float2*)(inputs + off);
        #pragma unroll
        for (int j = 0; j < NJ; ++j) {
            int f = lane + 64 * j;
            r[j] = (f < NF2) ? row[f] : make_float2(0.f, 0.f);
        }
    };

    auto process = [&](const float2* r) {    // caller guarantees row index < cnt
        float s = 0.f;
        #pragma unroll
        for (int j = 0; j < NJ; ++j) {
            s = fmaf(r[j].x, rel_r[j].x, s);
            s = fmaf(r[j].y, rel_r[j].y, s);
        }
        #pragma unroll
        for (int off = 32; off; off >>= 1) s += __shfl_xor(s, off);
        float w = __expf(s);
        sw += w;
        #pragma unroll
        for (int j = 0; j < NJ; ++j) {
            acc[j].x = fmaf(w, r[j].x, acc[j].x);
            acc[j].y = fmaf(w, r[j].y, acc[j].y);
        }
    };

    load_row(A, 0);
    if (1 < cnt) load_row(B, 1);
    int m = 0;
    for (;;) {
        if (m + 2 < cnt) load_row(C, m + 2);
        process(A);                           // row m
        if (++m >= cnt) break;
        if (m + 2 < cnt) load_row(A, m + 2);
        process(B);                           // row m
        if (++m >= cnt) break;
        if (m + 2 < cnt) load_row(B, m + 2);
        process(C);                           // row m
        if (++m >= cnt) break;
    }

    const float inv = 1.0f / (sw + 1e-8f);
    float2* out2 = (float2*)(out_att + (size_t)p * DD);
    #pragma unroll
    for (int j = 0; j < NJ; ++j) {
        int f = lane + 64 * j;
        if (f < NF2) out2[f] = make_float2(acc[j].x * inv, acc[j].y * inv);
    }
}

extern "C" void kernel_launch(void* const* d_in, const int* in_sizes, int n_in,
                              void* d_out, int out_size, void* d_ws, size_t ws_size,
                              hipStream_t stream) {
    const float* inputs = (const float*)d_in[0];
    const float* emb    = (const float*)d_in[1];
    const int*   labels = (const int*)d_in[2];
    const int*   epid   = (const int*)d_in[3];

    const int n_sent = in_sizes[2];
    const int P      = out_size / (DD + 1);      // 8192 (att P*D + labels P)

    int* counts = (int*)d_ws;                    // P ints
    int* idxmat = counts + P;                    // P*64 ints

    float* out_att = (float*)d_out;
    float* out_lab = out_att + (size_t)P * DD;

    hipMemsetAsync(counts, 0, (size_t)P * sizeof(int), stream);
    sa_scatter_kernel<<<(n_sent + 255) / 256, 256, 0, stream>>>(
        epid, labels, n_sent, counts, idxmat, out_lab, P);

    const int nblk = (P + 1) / 2;                // 2 bags (waves) per 128-thread block
    sa_bag_wave_kernel<<<nblk, BLK, 0, stream>>>(inputs, emb, counts, idxmat,
                                                 out_att, P);
}

// Round 10
// 48.110 us; speedup vs baseline: 1.0628x; 1.0149x over previous
//
#include <hip/hip_runtime.h>
#include <math.h>

#define MAXC 56      // member slots per bag (true max ~25); slot 63 = bag label
#define BLK  128     // 2 waves per block
#define DD   690     // feature dim
#define NF2  345     // DD/2 float2 elements per row
#define NJ   6       // ceil(NF2/64)

__global__ void sa_scatter_kernel(const int* __restrict__ epid,
                                  const int* __restrict__ labels, int n_sent,
                                  int* __restrict__ counts, int* __restrict__ idxmat,
                                  float* __restrict__ out_lab, int P) {
    int i = blockIdx.x * blockDim.x + threadIdx.x;
    if (i >= n_sent) return;
    int q = epid[i];
    int r = atomicAdd(&counts[q], 1);
    if (r < MAXC) idxmat[(q << 6) + r] = i * DD;   // element offset, not index
    if (r == 0) {
        int lab = labels[i];                 // labels consistent within a bag
        idxmat[(q << 6) + 63] = lab;         // stash bag label next to the offsets
        out_lab[P - 1 - q] = (float)lab;     // second output written here
    }
}

// One wave per bag, single pass, no max-subtraction (scores ~N(0,0.5): exp is
// fp32-safe; epsilon differs ~1e-8 relative). Pair ping-pong whose prefetch is
// PINNED with sched_barrier(0) so the compiler cannot sink the loads into the
// consumer (VGPR 28-52 in earlier rounds proved it was serializing them).
__global__ __launch_bounds__(BLK, 2)
void sa_bag_wave_kernel(const float* __restrict__ inputs,
                        const float* __restrict__ emb,
                        const int* __restrict__ counts,
                        const int* __restrict__ idxmat,
                        float* __restrict__ out_att,
                        int P) {
    const int lane = threadIdx.x & 63;
    const int wid  = threadIdx.x >> 6;
    const int p = (blockIdx.x << 1) + wid;   // output bag index
    if (p >= P) return;
    const int q = P - 1 - p;                 // pair id (desc sort + reversed bincount)
    int cnt = counts[q];                     // L2-hot (scatter-dirty)
    if (cnt > MAXC) cnt = MAXC;
    const int* bag = idxmat + (q << 6);
    int myoff = (lane < cnt) ? bag[lane] : 0;   // element offset of this lane's row
    const int lab = bag[63];                 // stashed bag label

    // rel = emb[lab]: 146KB table -> L2/L3-resident
    const float2* rel2 = (const float2*)(emb + (size_t)lab * DD);
    float2 rel_r[NJ];
    #pragma unroll
    for (int j = 0; j < NJ; ++j) {
        int f = lane + 64 * j;
        rel_r[j] = (f < NF2) ? rel2[f] : make_float2(0.f, 0.f);
    }

    float2 acc[NJ];
    #pragma unroll
    for (int j = 0; j < NJ; ++j) acc[j] = make_float2(0.f, 0.f);
    float sw = 0.f;

    float2 A0[NJ], A1[NJ], B0[NJ], B1[NJ];

    auto issue_pair = [&](float2* r0, float2* r1, int base) {
        int i0 = __shfl(myoff, base & 63);       // idx>=cnt lanes hold 0 -> row 0 (weight 0)
        int i1 = __shfl(myoff, (base + 1) & 63);
        const float2* row0 = (const float2*)(inputs + i0);
        const float2* row1 = (const float2*)(inputs + i1);
        #pragma unroll
        for (int j = 0; j < NJ; ++j) {
            int f = lane + 64 * j;
            if (f < NF2) { r0[j] = row0[f]; r1[j] = row1[f]; }
            else         { r0[j] = make_float2(0.f, 0.f); r1[j] = make_float2(0.f, 0.f); }
        }
    };

    auto process_pair = [&](const float2* r0, const float2* r1, int base) {
        float s0 = 0.f, s1 = 0.f;
        #pragma unroll
        for (int j = 0; j < NJ; ++j) {
            s0 = fmaf(r0[j].x, rel_r[j].x, s0);
            s0 = fmaf(r0[j].y, rel_r[j].y, s0);
            s1 = fmaf(r1[j].x, rel_r[j].x, s1);
            s1 = fmaf(r1[j].y, rel_r[j].y, s1);
        }
        #pragma unroll
        for (int off = 32; off; off >>= 1) {     // two independent butterflies
            s0 += __shfl_xor(s0, off);
            s1 += __shfl_xor(s1, off);
        }
        float w0 = __expf(s0);                   // base < cnt always
        float w1 = (base + 1 < cnt) ? __expf(s1) : 0.f;
        sw += w0 + w1;
        #pragma unroll
        for (int j = 0; j < NJ; ++j) {
            acc[j].x = fmaf(w0, r0[j].x, acc[j].x);
            acc[j].x = fmaf(w1, r1[j].x, acc[j].x);
            acc[j].y = fmaf(w0, r0[j].y, acc[j].y);
            acc[j].y = fmaf(w1, r1[j].y, acc[j].y);
        }
    };

    const int npair = (cnt + 1) >> 1;
    issue_pair(A0, A1, 0);
    int m = 0;
    for (;;) {
        if (m + 1 < npair) issue_pair(B0, B1, 2 * (m + 1));
        __builtin_amdgcn_sched_barrier(0);       // prefetch may not sink below here
        process_pair(A0, A1, 2 * m);
        if (++m >= npair) break;
        if (m + 1 < npair) issue_pair(A0, A1, 2 * (m + 1));
        __builtin_amdgcn_sched_barrier(0);
        process_pair(B0, B1, 2 * m);
        if (++m >= npair) break;
    }

    const float inv = 1.0f / (sw + 1e-8f);
    float2* out2 = (float2*)(out_att + (size_t)p * DD);
    #pragma unroll
    for (int j = 0; j < NJ; ++j) {
        int f = lane + 64 * j;
        if (f < NF2) out2[f] = make_float2(acc[j].x * inv, acc[j].y * inv);
    }
}

extern "C" void kernel_launch(void* const* d_in, const int* in_sizes, int n_in,
                              void* d_out, int out_size, void* d_ws, size_t ws_size,
                              hipStream_t stream) {
    const float* inputs = (const float*)d_in[0];
    const float* emb    = (const float*)d_in[1];
    const int*   labels = (const int*)d_in[2];
    const int*   epid   = (const int*)d_in[3];

    const int n_sent = in_sizes[2];
    const int P      = out_size / (DD + 1);      // 8192 (att P*D + labels P)

    int* counts = (int*)d_ws;                    // P ints
    int* idxmat = counts + P;                    // P*64 ints

    float* out_att = (float*)d_out;
    float* out_lab = out_att + (size_t)P * DD;

    hipMemsetAsync(counts, 0, (size_t)P * sizeof(int), stream);
    sa_scatter_kernel<<<(n_sent + 255) / 256, 256, 0, stream>>>(
        epid, labels, n_sent, counts, idxmat, out_lab, P);

    const int nblk = (P + 1) / 2;                // 2 bags (waves) per 128-thread block
    sa_bag_wave_kernel<<<nblk, BLK, 0, stream>>>(inputs, emb, counts, idxmat,
                                                 out_att, P);
}